// Round 8
// baseline (149.085 us; speedup 1.0000x reference)
//
#include <hip/hip_runtime.h>
#include <hip/hip_fp16.h>

// Round-8: DIAGNOSTIC ABLATION. A = full kernel (R7), B = stream-only,
// C = gather-only. B/C write to d_ws only (offsets past the 4MB table),
// so d_out correctness is untouched. Purpose: decompose A's ~42us into
// streaming vs gather cost; three rounds of model-based predictions failed.

constexpr int HH = 512;
constexpr int WW = 512;

typedef float f32x4 __attribute__((ext_vector_type(4)));

__device__ __forceinline__ float Lx_val(const float* __restrict__ flow, int i, int j) {
    const float s = 2.0f / 511.0f;
    return fmaf((float)j + flow[(i << 9) + j + HH * WW], s, -1.0f);  // ch1
}
__device__ __forceinline__ float Ly_val(const float* __restrict__ flow, int i, int j) {
    const float s = 2.0f / 511.0f;
    return fmaf((float)i + flow[(i << 9) + j], s, -1.0f);            // ch0
}

__device__ __forceinline__ unsigned int pack_corner(const float* __restrict__ flow,
                                                    int i, int j) {
    __half2 h = __float22half2_rn(make_float2(Lx_val(flow, i, j), Ly_val(flow, i, j)));
    return *reinterpret_cast<unsigned int*>(&h);
}

// ---------------- Kernel 1: build quad table (4 MB) ----------------
__global__ __launch_bounds__(256) void build_T_kernel(const float* __restrict__ flow,
                                                      uint4* __restrict__ T) {
    int idx = blockIdx.x * 256 + threadIdx.x;   // 0 .. 262143
    int i = idx >> 9;
    int j = idx & 511;
    int ip = min(i + 1, 511);
    int jp = min(j + 1, 511);
    uint4 e;
    e.x = pack_corner(flow, i,  j);    // v00
    e.y = pack_corner(flow, i,  jp);   // v01
    e.z = pack_corner(flow, ip, j);    // v10
    e.w = pack_corner(flow, ip, jp);   // v11
    T[idx] = e;
}

__device__ __forceinline__ float2 h2f(unsigned int u) {
    __half2 h = *reinterpret_cast<__half2*>(&u);
    return __half22float2(h);
}

__device__ __forceinline__ float2 combine4(uint4 e, float xf, float yf) {
    float2 v00 = h2f(e.x);
    float2 v01 = h2f(e.y);
    float2 v10 = h2f(e.z);
    float2 v11 = h2f(e.w);
    float w00 = xf * yf;
    float w10 = xf * (1.0f - yf);
    float w01 = (1.0f - xf) * yf;
    float w11 = (1.0f - xf) * (1.0f - yf);
    float tx = w00 * v00.x + w10 * v10.x + w01 * v01.x + w11 * v11.x;
    float ty = w00 * v00.y + w10 * v10.y + w01 * v01.y + w11 * v11.y;
    return make_float2((ty + 1.0f) * 256.0f, (tx + 1.0f) * 256.0f);
}

__device__ __forceinline__ float2 point_scalar(const uint4* __restrict__ T,
                                               float x, float y, bool bil) {
    if (bil) {
        float xt = truncf(x), yt = truncf(y);
        int x0 = (int)xt, y0 = (int)yt;
        return combine4(T[(x0 << 9) + y0], x - xt, y - yt);
    } else {
        int xi = min((int)rintf(x), 511);
        int yi = min((int)rintf(y), 511);
        float2 t = h2f(T[(xi << 9) + yi].x);
        return make_float2((t.y + 1.0f) * 256.0f, (t.x + 1.0f) * 256.0f);
    }
}

__device__ __forceinline__ f32x4 slot2(const uint4* __restrict__ T, f32x4 p, bool bil) {
    float2 r0 = point_scalar(T, p.x, p.y, bil);
    float2 r1 = point_scalar(T, p.z, p.w, bil);
    return f32x4{r0.x, r0.y, r1.x, r1.y};
}

// ---------------- Kernel A: full (identical to round 7) ----------------
__global__ __launch_bounds__(256) void pst_kernel(const float* __restrict__ point,
                                                  const uint4* __restrict__ T,
                                                  const int* __restrict__ intep,
                                                  float* __restrict__ out,
                                                  int n) {
    const bool bil = (*intep != 0);
    const int nquads = n >> 1;
    const int slot0 = blockIdx.x * 1024 + threadIdx.x;

    const f32x4* pts  = reinterpret_cast<const f32x4*>(point);
    f32x4*       out4 = reinterpret_cast<f32x4*>(out);

    if (slot0 + 768 < nquads) {
        f32x4 p0 = __builtin_nontemporal_load(&pts[slot0]);
        f32x4 p1 = __builtin_nontemporal_load(&pts[slot0 + 256]);
        f32x4 p2 = __builtin_nontemporal_load(&pts[slot0 + 512]);
        f32x4 p3 = __builtin_nontemporal_load(&pts[slot0 + 768]);

        float x[8] = {p0.x, p0.z, p1.x, p1.z, p2.x, p2.z, p3.x, p3.z};
        float y[8] = {p0.y, p0.w, p1.y, p1.w, p2.y, p2.w, p3.y, p3.w};

        if (bil) {
            float xf[8], yf[8];
            int idx[8];
#pragma unroll
            for (int k = 0; k < 8; ++k) {
                float xt = truncf(x[k]), yt = truncf(y[k]);
                xf[k] = x[k] - xt;
                yf[k] = y[k] - yt;
                idx[k] = ((int)xt << 9) + (int)yt;
            }
            uint4 e[8];
#pragma unroll
            for (int k = 0; k < 8; ++k) e[k] = T[idx[k]];
            __builtin_amdgcn_sched_barrier(0);

            float2 r[8];
#pragma unroll
            for (int k = 0; k < 8; ++k) r[k] = combine4(e[k], xf[k], yf[k]);

            __builtin_nontemporal_store(f32x4{r[0].x, r[0].y, r[1].x, r[1].y}, &out4[slot0]);
            __builtin_nontemporal_store(f32x4{r[2].x, r[2].y, r[3].x, r[3].y}, &out4[slot0 + 256]);
            __builtin_nontemporal_store(f32x4{r[4].x, r[4].y, r[5].x, r[5].y}, &out4[slot0 + 512]);
            __builtin_nontemporal_store(f32x4{r[6].x, r[6].y, r[7].x, r[7].y}, &out4[slot0 + 768]);
        } else {
            const unsigned int* Tw = reinterpret_cast<const unsigned int*>(T);
            unsigned int v[8];
#pragma unroll
            for (int k = 0; k < 8; ++k) {
                int xi = min((int)rintf(x[k]), 511);
                int yi = min((int)rintf(y[k]), 511);
                v[k] = Tw[(((xi << 9) + yi) << 2)];
            }
            __builtin_amdgcn_sched_barrier(0);
            float2 t[8];
#pragma unroll
            for (int k = 0; k < 8; ++k) t[k] = h2f(v[k]);
            __builtin_nontemporal_store(
                f32x4{(t[0].y + 1.0f) * 256.0f, (t[0].x + 1.0f) * 256.0f,
                      (t[1].y + 1.0f) * 256.0f, (t[1].x + 1.0f) * 256.0f}, &out4[slot0]);
            __builtin_nontemporal_store(
                f32x4{(t[2].y + 1.0f) * 256.0f, (t[2].x + 1.0f) * 256.0f,
                      (t[3].y + 1.0f) * 256.0f, (t[3].x + 1.0f) * 256.0f}, &out4[slot0 + 256]);
            __builtin_nontemporal_store(
                f32x4{(t[4].y + 1.0f) * 256.0f, (t[4].x + 1.0f) * 256.0f,
                      (t[5].y + 1.0f) * 256.0f, (t[5].x + 1.0f) * 256.0f}, &out4[slot0 + 512]);
            __builtin_nontemporal_store(
                f32x4{(t[6].y + 1.0f) * 256.0f, (t[6].x + 1.0f) * 256.0f,
                      (t[7].y + 1.0f) * 256.0f, (t[7].x + 1.0f) * 256.0f}, &out4[slot0 + 768]);
        }
    } else {
#pragma unroll
        for (int k = 0; k < 4; ++k) {
            int s = slot0 + k * 256;
            if (s < nquads) {
                f32x4 p = pts[s];
                out4[s] = slot2(T, p, bil);
            }
        }
        if ((n & 1) && threadIdx.x == 0 && blockIdx.x == gridDim.x - 1) {
            const float2* pt2  = reinterpret_cast<const float2*>(point);
            float2*       out2 = reinterpret_cast<float2*>(out);
            float2 p = pt2[n - 1];
            out2[n - 1] = point_scalar(T, p.x, p.y, bil);
        }
    }
}

// ---------------- Kernel B: stream-only (loads + transform + stores, NO gathers) ----------------
__global__ __launch_bounds__(256) void stream_only_kernel(const float* __restrict__ point,
                                                          float* __restrict__ wsout,
                                                          int n) {
    const int nquads = n >> 1;
    const int slot0 = blockIdx.x * 1024 + threadIdx.x;
    const f32x4* pts = reinterpret_cast<const f32x4*>(point);
    f32x4* o = reinterpret_cast<f32x4*>(wsout);

    if (slot0 + 768 < nquads) {
        f32x4 p0 = __builtin_nontemporal_load(&pts[slot0]);
        f32x4 p1 = __builtin_nontemporal_load(&pts[slot0 + 256]);
        f32x4 p2 = __builtin_nontemporal_load(&pts[slot0 + 512]);
        f32x4 p3 = __builtin_nontemporal_load(&pts[slot0 + 768]);
        __builtin_nontemporal_store(p0 * 0.5f + 7.0f, &o[slot0]);
        __builtin_nontemporal_store(p1 * 0.5f + 7.0f, &o[slot0 + 256]);
        __builtin_nontemporal_store(p2 * 0.5f + 7.0f, &o[slot0 + 512]);
        __builtin_nontemporal_store(p3 * 0.5f + 7.0f, &o[slot0 + 768]);
    } else {
#pragma unroll
        for (int k = 0; k < 4; ++k) {
            int s = slot0 + k * 256;
            if (s < nquads) o[s] = pts[s] * 0.5f + 7.0f;
        }
    }
}

// ---------------- Kernel C: gather-only (loads + index + 8 gathers + combine, 8MB stores) ----------------
__global__ __launch_bounds__(256) void gather_only_kernel(const float* __restrict__ point,
                                                          const uint4* __restrict__ T,
                                                          const int* __restrict__ intep,
                                                          float* __restrict__ wsacc,
                                                          int n) {
    const bool bil = (*intep != 0);
    const int nquads = n >> 1;
    const int slot0 = blockIdx.x * 1024 + threadIdx.x;
    const int gtid  = blockIdx.x * 256 + threadIdx.x;
    const f32x4* pts = reinterpret_cast<const f32x4*>(point);
    f32x4* acc4 = reinterpret_cast<f32x4*>(wsacc);

    if (slot0 + 768 < nquads) {
        f32x4 p0 = __builtin_nontemporal_load(&pts[slot0]);
        f32x4 p1 = __builtin_nontemporal_load(&pts[slot0 + 256]);
        f32x4 p2 = __builtin_nontemporal_load(&pts[slot0 + 512]);
        f32x4 p3 = __builtin_nontemporal_load(&pts[slot0 + 768]);

        float x[8] = {p0.x, p0.z, p1.x, p1.z, p2.x, p2.z, p3.x, p3.z};
        float y[8] = {p0.y, p0.w, p1.y, p1.w, p2.y, p2.w, p3.y, p3.w};

        if (bil) {
            float xf[8], yf[8];
            int idx[8];
#pragma unroll
            for (int k = 0; k < 8; ++k) {
                float xt = truncf(x[k]), yt = truncf(y[k]);
                xf[k] = x[k] - xt;
                yf[k] = y[k] - yt;
                idx[k] = ((int)xt << 9) + (int)yt;
            }
            uint4 e[8];
#pragma unroll
            for (int k = 0; k < 8; ++k) e[k] = T[idx[k]];
            __builtin_amdgcn_sched_barrier(0);

            float2 r[8];
#pragma unroll
            for (int k = 0; k < 8; ++k) r[k] = combine4(e[k], xf[k], yf[k]);
            // reduce to one f32x4 per thread (keeps all gathers live, 1/4 store traffic)
            f32x4 a = {r[0].x + r[2].x + r[4].x + r[6].x,
                       r[0].y + r[2].y + r[4].y + r[6].y,
                       r[1].x + r[3].x + r[5].x + r[7].x,
                       r[1].y + r[3].y + r[5].y + r[7].y};
            __builtin_nontemporal_store(a, &acc4[gtid]);
        } else {
            const unsigned int* Tw = reinterpret_cast<const unsigned int*>(T);
            unsigned int v[8];
#pragma unroll
            for (int k = 0; k < 8; ++k) {
                int xi = min((int)rintf(x[k]), 511);
                int yi = min((int)rintf(y[k]), 511);
                v[k] = Tw[(((xi << 9) + yi) << 2)];
            }
            __builtin_amdgcn_sched_barrier(0);
            f32x4 a = {0.f, 0.f, 0.f, 0.f};
#pragma unroll
            for (int k = 0; k < 8; ++k) { float2 t = h2f(v[k]); a.x += t.x; a.y += t.y; }
            __builtin_nontemporal_store(a, &acc4[gtid]);
        }
    } else if (gtid < (nquads + 3) / 4 + 1) {
        f32x4 a = {0.f, 0.f, 0.f, 0.f};
        acc4[gtid] = a;
    }
}

extern "C" void kernel_launch(void* const* d_in, const int* in_sizes, int n_in,
                              void* d_out, int out_size, void* d_ws, size_t ws_size,
                              hipStream_t stream) {
    const float* point = (const float*)d_in[0];  // (1, N, 2)
    const float* flow  = (const float*)d_in[1];  // (1, 2, 512, 512)
    const int*   intep = (const int*)d_in[2];    // scalar
    float* out = (float*)d_out;                  // (1, N, 2)

    const int n = in_sizes[0] / 2;               // number of points

    uint4* T = (uint4*)d_ws;                     // [0, 4MB): table

    build_T_kernel<<<HH * WW / 256, 256, 0, stream>>>(flow, T);

    const int nquads = n >> 1;
    int blocks = (nquads + 1023) / 1024;
    if (blocks < 1) blocks = 1;

    // A: real output
    pst_kernel<<<blocks, 256, 0, stream>>>(point, T, intep, out, n);

    // B + C diagnostics into d_ws (need 4MB table + regions below 72MB)
    if (ws_size >= (size_t)80 << 20) {
        float* wsB = (float*)((char*)d_ws + ((size_t)16 << 20)); // 32MB region
        float* wsC = (float*)((char*)d_ws + ((size_t)64 << 20)); // 8MB region
        stream_only_kernel<<<blocks, 256, 0, stream>>>(point, wsB, n);
        gather_only_kernel<<<blocks, 256, 0, stream>>>(point, T, intep, wsC, n);
    }
}